// Round 3
// baseline (191.878 us; speedup 1.0000x reference)
//
#include <hip/hip_runtime.h>
#include <hip/hip_bf16.h>

typedef short s16x8 __attribute__((ext_vector_type(8)));
typedef float f32x4 __attribute__((ext_vector_type(4)));

#define BB 32
#define SS 2048
#define DD 64
#define QBLK 128
#define KVBLK 32
#define NQB (SS / QBLK)          // 16
#define NTILES (SS / KVBLK)      // 64

// Q pre-scale folds 1/sqrt(64) and log2(e): softmax done in exp2 domain.
#define QSCALE (0.125f * 1.44269504088896340736f)

// LDS map (bytes): K [32][64]bf16 swz @0 (4KB) ; Vt [64][32]bf16 swz @4096 (4KB);
// P per-wave per-qs [16][32]bf16 swz @8192 + w*2048 + qs*1024 (8KB). Total 16KB.
#define K_OFF 0
#define V_OFF 4096
#define P_OFF 8192

__device__ __forceinline__ short f2bf(float f) {
  union { float f; unsigned u; } x; x.f = f;
  unsigned r = (x.u + 0x7FFF + ((x.u >> 16) & 1)) >> 16;  // RNE
  return (short)r;
}

__global__ __launch_bounds__(256, 2)
void attn_fwd(const float* __restrict__ Q, const float* __restrict__ K,
              const float* __restrict__ V, float* __restrict__ O) {
  __shared__ __align__(16) char smem[16384];
  const int tid  = threadIdx.x;
  const int w    = tid >> 6;
  const int lane = tid & 63;
  const int l15  = lane & 15;
  const int l16  = lane >> 4;

  const int bid   = blockIdx.x;
  const int batch = bid >> 4;        // NQB = 16
  const int qb    = bid & 15;
  const int qbase = qb * QBLK + w * 32;

  const size_t bstride = (size_t)batch * SS * DD;

  // ---- Q fragments (held in regs for whole kernel), pre-scaled ----
  s16x8 aq[2][2];
#pragma unroll
  for (int qs = 0; qs < 2; ++qs)
#pragma unroll
    for (int dh = 0; dh < 2; ++dh) {
      const float* qp = Q + bstride + (size_t)(qbase + qs * 16 + l15) * DD + dh * 32 + l16 * 8;
      const float4 x = *(const float4*)qp;
      const float4 y = *(const float4*)(qp + 4);
      s16x8 v;
      v[0] = f2bf(x.x * QSCALE); v[1] = f2bf(x.y * QSCALE);
      v[2] = f2bf(x.z * QSCALE); v[3] = f2bf(x.w * QSCALE);
      v[4] = f2bf(y.x * QSCALE); v[5] = f2bf(y.y * QSCALE);
      v[6] = f2bf(y.z * QSCALE); v[7] = f2bf(y.w * QSCALE);
      aq[qs][dh] = v;
    }

  f32x4 oacc[2][4];
#pragma unroll
  for (int qs = 0; qs < 2; ++qs)
#pragma unroll
    for (int dc = 0; dc < 4; ++dc)
      oacc[qs][dc] = (f32x4){0.f, 0.f, 0.f, 0.f};
  float mrun[2][4], lrun[2][4];
#pragma unroll
  for (int qs = 0; qs < 2; ++qs)
#pragma unroll
    for (int r = 0; r < 4; ++r) { mrun[qs][r] = -1e30f; lrun[qs][r] = 0.f; }

  // ---- staging address precompute ----
  const int krow  = tid >> 3;            // 0..31
  const int kslot = tid & 7;             // 0..7  (d-chunk of 8)
  const float* kg = K + bstride + (size_t)krow * DD + kslot * 8;
  char* kls = smem + K_OFF + krow * 128 + ((kslot ^ (krow & 7)) << 4);
  const float* vg = V + bstride + lane;  // column d = lane, rows k = w*8+j
  char* vls = smem + V_OFF + lane * 64 + ((w ^ ((lane >> 1) & 3)) << 4);

  for (int t = 0; t < NTILES; ++t) {
    const int kb = t * KVBLK;
    __syncthreads();
    // stage K tile -> LDS (bf16, XOR-swizzled), 1 ds_write_b128/thread
    {
      const float* g = kg + (size_t)kb * DD;
      const float4 x = *(const float4*)g;
      const float4 y = *(const float4*)(g + 4);
      s16x8 kv;
      kv[0] = f2bf(x.x); kv[1] = f2bf(x.y); kv[2] = f2bf(x.z); kv[3] = f2bf(x.w);
      kv[4] = f2bf(y.x); kv[5] = f2bf(y.y); kv[6] = f2bf(y.z); kv[7] = f2bf(y.w);
      *(s16x8*)kls = kv;
    }
    // stage V tile transposed -> LDS (coalesced reads, 1 ds_write_b128/lane)
    {
      s16x8 vv;
#pragma unroll
      for (int j = 0; j < 8; ++j)
        vv[j] = f2bf(vg[(size_t)(kb + w * 8 + j) * DD]);
      *(s16x8*)vls = vv;
    }
    __syncthreads();

    // K B-frags: lane holds K[kc*16+l15][dh*32 + l16*8 + j]
    s16x8 bk[2][2];
#pragma unroll
    for (int kc = 0; kc < 2; ++kc) {
      const int row = kc * 16 + l15;
#pragma unroll
      for (int dh = 0; dh < 2; ++dh) {
        const int slot = dh * 4 + l16;
        bk[kc][dh] = *(const s16x8*)(smem + K_OFF + row * 128 + ((slot ^ (row & 7)) << 4));
      }
    }
    // V B-frags: lane holds V[kb + l16*8 + j][dc*16 + l15]
    s16x8 bv[4];
#pragma unroll
    for (int dc = 0; dc < 4; ++dc) {
      const int row = dc * 16 + l15;
      bv[dc] = *(const s16x8*)(smem + V_OFF + row * 64 + ((l16 ^ ((row >> 1) & 3)) << 4));
    }

#pragma unroll
    for (int qs = 0; qs < 2; ++qs) {
      f32x4 sc0 = (f32x4){0.f, 0.f, 0.f, 0.f};
      f32x4 sc1 = (f32x4){0.f, 0.f, 0.f, 0.f};
      sc0 = __builtin_amdgcn_mfma_f32_16x16x32_bf16(aq[qs][0], bk[0][0], sc0, 0, 0, 0);
      sc0 = __builtin_amdgcn_mfma_f32_16x16x32_bf16(aq[qs][1], bk[0][1], sc0, 0, 0, 0);
      sc1 = __builtin_amdgcn_mfma_f32_16x16x32_bf16(aq[qs][0], bk[1][0], sc1, 0, 0, 0);
      sc1 = __builtin_amdgcn_mfma_f32_16x16x32_bf16(aq[qs][1], bk[1][1], sc1, 0, 0, 0);

      // ---- online softmax (rows r of this 16-q subtile; cols across 16 lanes) ----
      float p0[4], p1[4], scl[4];
#pragma unroll
      for (int r = 0; r < 4; ++r) {
        float mx = fmaxf(sc0[r], sc1[r]);
#pragma unroll
        for (int msk = 8; msk >= 1; msk >>= 1) mx = fmaxf(mx, __shfl_xor(mx, msk));
        const float mnew = fmaxf(mrun[qs][r], mx);
        scl[r] = exp2f(mrun[qs][r] - mnew);
        p0[r] = exp2f(sc0[r] - mnew);
        p1[r] = exp2f(sc1[r] - mnew);
        float s = p0[r] + p1[r];
#pragma unroll
        for (int msk = 8; msk >= 1; msk >>= 1) s += __shfl_xor(s, msk);
        lrun[qs][r] = lrun[qs][r] * scl[r] + s;
        mrun[qs][r] = mnew;
      }
#pragma unroll
      for (int dc = 0; dc < 4; ++dc) {
        f32x4 o = oacc[qs][dc];
#pragma unroll
        for (int r = 0; r < 4; ++r) o[r] *= scl[r];
        oacc[qs][dc] = o;
      }

      // ---- P -> LDS (bf16, swizzled), then reread as MFMA A-frag ----
      char* pw = smem + P_OFF + w * 2048 + qs * 1024;
#pragma unroll
      for (int r = 0; r < 4; ++r) {
        const int q  = l16 * 4 + r;
        const int sw = (q >> 1) & 3;
        *(short*)(pw + q * 64 + ((((l15 >> 3) + 0) ^ sw) << 4) + (lane & 7) * 2) = f2bf(p0[r]);
        *(short*)(pw + q * 64 + ((((l15 >> 3) + 2) ^ sw) << 4) + (lane & 7) * 2) = f2bf(p1[r]);
      }
      asm volatile("s_waitcnt lgkmcnt(0)" ::: "memory");
      const s16x8 pa = *(const s16x8*)(pw + l15 * 64 + ((l16 ^ ((l15 >> 1) & 3)) << 4));

#pragma unroll
      for (int dc = 0; dc < 4; ++dc)
        oacc[qs][dc] = __builtin_amdgcn_mfma_f32_16x16x32_bf16(pa, bv[dc], oacc[qs][dc], 0, 0, 0);
    }
  }

  // ---- epilogue: O = acc / l ----
#pragma unroll
  for (int qs = 0; qs < 2; ++qs) {
    float inv[4];
#pragma unroll
    for (int r = 0; r < 4; ++r) inv[r] = 1.0f / lrun[qs][r];
#pragma unroll
    for (int dc = 0; dc < 4; ++dc)
#pragma unroll
      for (int r = 0; r < 4; ++r) {
        const int row = qbase + qs * 16 + l16 * 4 + r;
        O[bstride + (size_t)row * DD + dc * 16 + l15] = oacc[qs][dc][r] * inv[r];
      }
  }
}

extern "C" void kernel_launch(void* const* d_in, const int* in_sizes, int n_in,
                              void* d_out, int out_size, void* d_ws, size_t ws_size,
                              hipStream_t stream) {
  const float* Q = (const float*)d_in[0];
  const float* K = (const float*)d_in[1];
  const float* V = (const float*)d_in[2];
  float* Oo = (float*)d_out;
  dim3 grid(BB * NQB);   // 512
  dim3 block(256);
  hipLaunchKernelGGL(attn_fwd, grid, block, 0, stream, Q, K, V, Oo);
}

// Round 5
// 132.340 us; speedup vs baseline: 1.4499x; 1.4499x over previous
//
#include <hip/hip_runtime.h>

typedef short    s16x8 __attribute__((ext_vector_type(8)));
typedef float    f32x4 __attribute__((ext_vector_type(4)));
typedef unsigned u32x2 __attribute__((ext_vector_type(2)));
typedef unsigned u32x4 __attribute__((ext_vector_type(4)));

#define BB 32
#define SS 2048
#define DD 64
#define QBLK 128
#define KVBLK 32
#define NQB (SS / QBLK)          // 16
#define NTILES (SS / KVBLK)      // 64

// Q pre-scale folds 1/sqrt(64) and log2(e): softmax in exp2 domain.
#define QSCALE (0.125f * 1.44269504088896340736f)

// LDS: K [32][64]bf16, 16B-slot XOR swizzle (slot^row&7), 4KB @0.
//      Vt [64 d][32 k']bf16, k' = g*8+kc*4+r permutation, 8B-slot XOR swizzle
//      (slot ^ (d&6), even so b128 frag reads stay contiguous), 4KB @4096.
#define K_OFF 0
#define V_OFF 4096

union U8 { u32x4 u; s16x8 s; };

__device__ __forceinline__ unsigned pk2bf(float lo, float hi) {
  unsigned r;
  asm("v_cvt_pk_bf16_f32 %0, %1, %2" : "=v"(r) : "v"(lo), "v"(hi));
  return r;
}

__global__ __launch_bounds__(512, 4)
void attn_fwd(const float* __restrict__ Q, const float* __restrict__ K,
              const float* __restrict__ V, float* __restrict__ O) {
  __shared__ __align__(16) char smem[8192];
  const int tid  = threadIdx.x;
  const int w    = tid >> 6;          // 0..7
  const int lane = tid & 63;
  const int l15  = lane & 15;
  const int l16  = lane >> 4;

  const int bid   = blockIdx.x;
  const int batch = bid >> 4;         // NQB = 16
  const int qb    = bid & 15;
  const size_t bstride = (size_t)batch * SS * DD;
  const int qrow0 = qb * QBLK + w * 16;

  // ---- Q B-frags (col=q=l15, k=d=dh*32+l16*8+j), pre-scaled ----
  s16x8 aq[2];
#pragma unroll
  for (int dh = 0; dh < 2; ++dh) {
    const float* qp = Q + bstride + (size_t)(qrow0 + l15) * DD + dh * 32 + l16 * 8;
    const float4 x = *(const float4*)qp;
    const float4 y = *(const float4*)(qp + 4);
    U8 u;
    u.u = (u32x4){ pk2bf(x.x * QSCALE, x.y * QSCALE), pk2bf(x.z * QSCALE, x.w * QSCALE),
                   pk2bf(y.x * QSCALE, y.y * QSCALE), pk2bf(y.z * QSCALE, y.w * QSCALE) };
    aq[dh] = u.s;
  }

  // Accumulators: O^T tiles, lane holds q=l15, d = dt*16 + l16*4 + r.
  f32x4 oT[4];
#pragma unroll
  for (int dt = 0; dt < 4; ++dt) oT[dt] = (f32x4){0.f, 0.f, 0.f, 0.f};
  float mrun = -1e30f, lrun = 0.f;

  // ---- staging addresses ----
  // waves 0-3: V stager. lane = d column; rows k = w*8+j. Writes k'-permuted.
  const float* gV = V + bstride + lane;
  const int vs0 = (w & 1) * 4 + (w >> 1);
  char* vls0 = smem + V_OFF + lane * 64 + (((vs0 + 0) ^ (lane & 6)) << 3);
  char* vls1 = smem + V_OFF + lane * 64 + (((vs0 + 2) ^ (lane & 6)) << 3);
  // waves 4-7: K stager. row = tp>>3, 8-float chunk = tp&7.
  const int tp   = tid - 256;
  const int krow = tp >> 3, kch = tp & 7;
  const float* gK = K + bstride + (size_t)krow * DD + kch * 8;
  char* kls = smem + K_OFF + krow * 128 + ((kch ^ (krow & 7)) << 4);

  float4 ra, rb, rc, rd;  // stage regs: set A (ra,rb), set B (rc,rd)

  auto stage_load = [&](int t, float4& x, float4& y) {
    const int kb = t * KVBLK;
    if (w < 4) {
      const float* g = gV + (size_t)(kb + w * 8) * DD;
      x.x = g[0 * DD]; x.y = g[1 * DD]; x.z = g[2 * DD]; x.w = g[3 * DD];
      y.x = g[4 * DD]; y.y = g[5 * DD]; y.z = g[6 * DD]; y.w = g[7 * DD];
    } else {
      const float* g = gK + (size_t)kb * DD;
      x = *(const float4*)g;
      y = *(const float4*)(g + 4);
    }
  };
  auto stage_write = [&](const float4& x, const float4& y) {
    if (w < 4) {
      u32x2 lo = (u32x2){ pk2bf(x.x, x.y), pk2bf(x.z, x.w) };
      u32x2 hi = (u32x2){ pk2bf(y.x, y.y), pk2bf(y.z, y.w) };
      *(u32x2*)vls0 = lo;
      *(u32x2*)vls1 = hi;
    } else {
      u32x4 kv = (u32x4){ pk2bf(x.x, x.y), pk2bf(x.z, x.w),
                          pk2bf(y.x, y.y), pk2bf(y.z, y.w) };
      *(u32x4*)kls = kv;
    }
  };

  auto compute = [&]() {
    // K A-frags: lane holds K[kc*16+l15][dh*32+l16*8+j]
    s16x8 bk[2][2];
#pragma unroll
    for (int kc = 0; kc < 2; ++kc)
#pragma unroll
      for (int dh = 0; dh < 2; ++dh)
        bk[kc][dh] = *(const s16x8*)(smem + K_OFF + (kc * 16 + l15) * 128 +
                                     (((dh * 4 + l16) ^ (l15 & 7)) << 4));
    // V^T A-frags: b128 = k' = l16*8..+7 for d-row dt*16+l15
    s16x8 vt[4];
#pragma unroll
    for (int dt = 0; dt < 4; ++dt)
      vt[dt] = *(const s16x8*)(smem + V_OFF + (dt * 16 + l15) * 64 +
                               (((2 * l16) ^ (l15 & 6)) << 3));

    // S^T = K·Q^T : lane holds q=l15, k = kc*16 + l16*4 + r
    f32x4 s0 = (f32x4){0.f, 0.f, 0.f, 0.f};
    f32x4 s1 = (f32x4){0.f, 0.f, 0.f, 0.f};
    s0 = __builtin_amdgcn_mfma_f32_16x16x32_bf16(bk[0][0], aq[0], s0, 0, 0, 0);
    s0 = __builtin_amdgcn_mfma_f32_16x16x32_bf16(bk[0][1], aq[1], s0, 0, 0, 0);
    s1 = __builtin_amdgcn_mfma_f32_16x16x32_bf16(bk[1][0], aq[0], s1, 0, 0, 0);
    s1 = __builtin_amdgcn_mfma_f32_16x16x32_bf16(bk[1][1], aq[1], s1, 0, 0, 0);

    // ---- online softmax: in-lane over 8 scores + 2 shfls across l16 groups ----
    float mx = fmaxf(fmaxf(fmaxf(s0[0], s1[0]), fmaxf(s0[1], s1[1])),
                     fmaxf(fmaxf(s0[2], s1[2]), fmaxf(s0[3], s1[3])));
    mx = fmaxf(mx, __shfl_xor(mx, 16));
    mx = fmaxf(mx, __shfl_xor(mx, 32));
    const float mnew = fmaxf(mrun, mx);
    const float scl = __builtin_amdgcn_exp2f(mrun - mnew);
    float p0[4], p1[4];
#pragma unroll
    for (int r = 0; r < 4; ++r) {
      p0[r] = __builtin_amdgcn_exp2f(s0[r] - mnew);
      p1[r] = __builtin_amdgcn_exp2f(s1[r] - mnew);
    }
    float sm = ((p0[0] + p0[1]) + (p0[2] + p0[3])) + ((p1[0] + p1[1]) + (p1[2] + p1[3]));
    sm += __shfl_xor(sm, 16);
    sm += __shfl_xor(sm, 32);
    lrun = lrun * scl + sm;
    mrun = mnew;

    // P B-frag directly in regs: position j holds P[q][(j>>2)*16 + l16*4 + (j&3)]
    U8 pb;
    pb.u = (u32x4){ pk2bf(p0[0], p0[1]), pk2bf(p0[2], p0[3]),
                    pk2bf(p1[0], p1[1]), pk2bf(p1[2], p1[3]) };

    // O^T += V^T · P^T  (k-permutation identical on A and B sides)
#pragma unroll
    for (int dt = 0; dt < 4; ++dt) {
      oT[dt] = oT[dt] * scl;
      oT[dt] = __builtin_amdgcn_mfma_f32_16x16x32_bf16(vt[dt], pb.s, oT[dt], 0, 0, 0);
    }
  };

  // ---- main loop: T14 async-stage, unroll-2 reg ping-pong (static indexing) ----
  stage_load(0, ra, rb);
  for (int t = 0; t < NTILES; t += 2) {
    __syncthreads();
    stage_write(ra, rb);
    stage_load(t + 1, rc, rd);
    __syncthreads();
    compute();

    __syncthreads();
    stage_write(rc, rd);
    stage_load(t + 2 < NTILES ? t + 2 : NTILES - 1, ra, rb);
    __syncthreads();
    compute();
  }

  // ---- epilogue ----
  const float inv = 1.0f / lrun;
  float* ob = O + bstride + (size_t)(qrow0 + l15) * DD + l16 * 4;
#pragma unroll
  for (int dt = 0; dt < 4; ++dt)
#pragma unroll
    for (int r = 0; r < 4; ++r)
      ob[dt * 16 + r] = oT[dt][r] * inv;
}

extern "C" void kernel_launch(void* const* d_in, const int* in_sizes, int n_in,
                              void* d_out, int out_size, void* d_ws, size_t ws_size,
                              hipStream_t stream) {
  const float* Q = (const float*)d_in[0];
  const float* K = (const float*)d_in[1];
  const float* V = (const float*)d_in[2];
  float* Oo = (float*)d_out;
  dim3 grid(BB * NQB);   // 512
  dim3 block(512);       // 8 waves
  hipLaunchKernelGGL(attn_fwd, grid, block, 0, stream, Q, K, V, Oo);
}

// Round 7
// 131.183 us; speedup vs baseline: 1.4627x; 1.0088x over previous
//
#include <hip/hip_runtime.h>

typedef short    s16x8 __attribute__((ext_vector_type(8)));
typedef float    f32x4 __attribute__((ext_vector_type(4)));
typedef unsigned u32x4 __attribute__((ext_vector_type(4)));

#define BB 32
#define SS 2048
#define DD 64
#define QBLK 128
#define KVBLK 32
#define NQB (SS / QBLK)          // 16
#define NTILES (SS / KVBLK)      // 64

#define QSCALE (0.125f * 1.44269504088896340736f)

// Double-buffered LDS. Per buffer: K [32][64]bf16, 16B-slot XOR (kch^row&7), 4KB @0;
// Vt [64 d][32 k' padded to 64] bf16, row stride 128B, 16B-slot XOR (g^(d&7)), 8KB @4096.
#define BUFSZ 12288
#define K_OFF 0
#define V_OFF 4096

union U8 { u32x4 u; s16x8 s; };

__device__ __forceinline__ unsigned pk2bf(float lo, float hi) {
  unsigned r;
  asm("v_cvt_pk_bf16_f32 %0, %1, %2" : "=v"(r) : "v"(lo), "v"(hi));
  return r;
}

// Raw barrier: drain LDS ops only (NOT vmem) then sync. Keeps prefetch loads in flight.
#define BARRIER() asm volatile("s_waitcnt lgkmcnt(0)\ns_barrier" ::: "memory")

__global__ __launch_bounds__(512, 4)
void attn_fwd(const float* __restrict__ Q, const float* __restrict__ K,
              const float* __restrict__ V, float* __restrict__ O) {
  __shared__ __align__(16) char smem[2 * BUFSZ];
  const int tid  = threadIdx.x;
  const int w    = tid >> 6;          // 0..7
  const int lane = tid & 63;
  const int l15  = lane & 15;
  const int l16  = lane >> 4;

  // XCD-aware swizzle: contiguous wid chunk per XCD -> 4 batches per XCD L2.
  const int bid0  = blockIdx.x;
  const int wid   = (bid0 & 7) * 64 + (bid0 >> 3);
  const int batch = wid >> 4;
  const int qb    = wid & 15;
  const size_t bstride = (size_t)batch * SS * DD;
  const int qrow0 = qb * QBLK + w * 16;

  // ---- Q B-frags (col=q=l15, k=d=dh*32+l16*8+j), pre-scaled ----
  s16x8 aq[2];
#pragma unroll
  for (int dh = 0; dh < 2; ++dh) {
    const float* qp = Q + bstride + (size_t)(qrow0 + l15) * DD + dh * 32 + l16 * 8;
    const float4 x = *(const float4*)qp;
    const float4 y = *(const float4*)(qp + 4);
    U8 u;
    u.u = (u32x4){ pk2bf(x.x * QSCALE, x.y * QSCALE), pk2bf(x.z * QSCALE, x.w * QSCALE),
                   pk2bf(y.x * QSCALE, y.y * QSCALE), pk2bf(y.z * QSCALE, y.w * QSCALE) };
    aq[dh] = u.s;
  }

  // O^T accumulators: lane holds q=l15, d = dt*16 + l16*4 + r.
  f32x4 oT[4];
#pragma unroll
  for (int dt = 0; dt < 4; ++dt) oT[dt] = (f32x4){0.f, 0.f, 0.f, 0.f};
  float mrun = -1e30f, lrun = 0.f;

  // ---- staging addresses ----
  // waves 0-3 (g=w): V stager. lane = d column; loads k rows {g*4+r, 16+g*4+r}
  // -> k' = g*8..g*8+7 contiguous -> ONE b128 write at slot g^(d&7).
  const float* gV = V + bstride + lane;
  const int vls_off = V_OFF + lane * 128 + ((w ^ (lane & 7)) << 4);
  // waves 4-7: K stager. row = tp>>3, 8-float chunk = tp&7.
  const int tp   = tid - 256;
  const int krow = tp >> 3, kch = tp & 7;
  const float* gK = K + bstride + (size_t)krow * DD + kch * 8;
  const int kls_off = K_OFF + krow * 128 + ((kch ^ (krow & 7)) << 4);

  float4 ra, rb, rc, rd;  // prefetch reg sets

  auto stage_load = [&](int t, float4& x, float4& y) {
    const int kb = t * KVBLK;
    if (w < 4) {
      const float* g0 = gV + (size_t)(kb + w * 4) * DD;
      x.x = g0[0];          x.y = g0[DD];          x.z = g0[2 * DD];          x.w = g0[3 * DD];
      const float* g1 = g0 + 16 * DD;
      y.x = g1[0];          y.y = g1[DD];          y.z = g1[2 * DD];          y.w = g1[3 * DD];
    } else {
      const float* g = gK + (size_t)kb * DD;
      x = *(const float4*)g;
      y = *(const float4*)(g + 4);
    }
  };
  auto stage_write = [&](int off, const float4& x, const float4& y) {
    u32x4 v = (u32x4){ pk2bf(x.x, x.y), pk2bf(x.z, x.w),
                       pk2bf(y.x, y.y), pk2bf(y.z, y.w) };
    *(u32x4*)(smem + off + (w < 4 ? vls_off : kls_off)) = v;
  };

  auto compute = [&](int off) {
    // K A-frags: lane holds K[kc*16+l15][dh*32+l16*8+j]
    s16x8 bk[2][2];
#pragma unroll
    for (int kc = 0; kc < 2; ++kc)
#pragma unroll
      for (int dh = 0; dh < 2; ++dh)
        bk[kc][dh] = *(const s16x8*)(smem + off + K_OFF + (kc * 16 + l15) * 128 +
                                     (((dh * 4 + l16) ^ (l15 & 7)) << 4));
    // V^T A-frags: k' chunk l16 of d-row dt*16+l15
    s16x8 vt[4];
#pragma unroll
    for (int dt = 0; dt < 4; ++dt)
      vt[dt] = *(const s16x8*)(smem + off + V_OFF + (dt * 16 + l15) * 128 +
                               ((l16 ^ (l15 & 7)) << 4));

    // S^T = K·Q^T : lane holds q=l15, k = kc*16 + l16*4 + r
    f32x4 s0 = (f32x4){0.f, 0.f, 0.f, 0.f};
    f32x4 s1 = (f32x4){0.f, 0.f, 0.f, 0.f};
    __builtin_amdgcn_s_setprio(1);
    s0 = __builtin_amdgcn_mfma_f32_16x16x32_bf16(bk[0][0], aq[0], s0, 0, 0, 0);
    s0 = __builtin_amdgcn_mfma_f32_16x16x32_bf16(bk[0][1], aq[1], s0, 0, 0, 0);
    s1 = __builtin_amdgcn_mfma_f32_16x16x32_bf16(bk[1][0], aq[0], s1, 0, 0, 0);
    s1 = __builtin_amdgcn_mfma_f32_16x16x32_bf16(bk[1][1], aq[1], s1, 0, 0, 0);
    __builtin_amdgcn_s_setprio(0);

    // ---- online softmax, defer-max (THR=8 in log2 domain) ----
    float mx = fmaxf(fmaxf(fmaxf(s0[0], s1[0]), fmaxf(s0[1], s1[1])),
                     fmaxf(fmaxf(s0[2], s1[2]), fmaxf(s0[3], s1[3])));
    mx = fmaxf(mx, __shfl_xor(mx, 16));
    mx = fmaxf(mx, __shfl_xor(mx, 32));
    const int skip = __all(mx <= mrun + 8.0f);
    float mnew = mrun, scl;
    if (!skip) {
      mnew = fmaxf(mrun, mx);
      scl  = __builtin_amdgcn_exp2f(mrun - mnew);
    }
    float p0[4], p1[4];
#pragma unroll
    for (int r = 0; r < 4; ++r) {
      p0[r] = __builtin_amdgcn_exp2f(s0[r] - mnew);
      p1[r] = __builtin_amdgcn_exp2f(s1[r] - mnew);
    }
    float sm = ((p0[0] + p0[1]) + (p0[2] + p0[3])) + ((p1[0] + p1[1]) + (p1[2] + p1[3]));
    sm += __shfl_xor(sm, 16);
    sm += __shfl_xor(sm, 32);
    if (!skip) {
      lrun *= scl;
#pragma unroll
      for (int dt = 0; dt < 4; ++dt) oT[dt] = oT[dt] * scl;
      mrun = mnew;
    }
    lrun += sm;

    // P B-frag in regs: position j holds P[q][(j>>2)*16 + l16*4 + (j&3)]
    U8 pb;
    pb.u = (u32x4){ pk2bf(p0[0], p0[1]), pk2bf(p0[2], p0[3]),
                    pk2bf(p1[0], p1[1]), pk2bf(p1[2], p1[3]) };

    // O^T += V^T · P^T (same k' permutation on A and B sides)
    __builtin_amdgcn_s_setprio(1);
#pragma unroll
    for (int dt = 0; dt < 4; ++dt)
      oT[dt] = __builtin_amdgcn_mfma_f32_16x16x32_bf16(vt[dt], pb.s, oT[dt], 0, 0, 0);
    __builtin_amdgcn_s_setprio(0);
  };

  // ---- pipelined main loop: 1 raw barrier per tile, loads fly across barriers ----
  stage_load(0, ra, rb);
  stage_write(0, ra, rb);
  BARRIER();
  for (int i = 0; i < 31; ++i) {
    stage_load(2 * i + 1, rc, rd);
    compute(0);
    stage_write(BUFSZ, rc, rd);
    BARRIER();
    stage_load(2 * i + 2, ra, rb);
    compute(BUFSZ);
    stage_write(0, ra, rb);
    BARRIER();
  }
  stage_load(63, rc, rd);
  compute(0);                 // tile 62
  stage_write(BUFSZ, rc, rd);
  BARRIER();
  compute(BUFSZ);             // tile 63

  // ---- epilogue ----
  const float inv = 1.0f / lrun;
  float* ob = O + bstride + (size_t)(qrow0 + l15) * DD + l16 * 4;
#pragma unroll
  for (int dt = 0; dt < 4; ++dt)
#pragma unroll
    for (int r = 0; r < 4; ++r)
      ob[dt * 16 + r] = oT[dt][r] * inv;
}

extern "C" void kernel_launch(void* const* d_in, const int* in_sizes, int n_in,
                              void* d_out, int out_size, void* d_ws, size_t ws_size,
                              hipStream_t stream) {
  const float* Q = (const float*)d_in[0];
  const float* K = (const float*)d_in[1];
  const float* V = (const float*)d_in[2];
  float* Oo = (float*)d_out;
  dim3 grid(BB * NQB);   // 512
  dim3 block(512);       // 8 waves
  hipLaunchKernelGGL(attn_fwd, grid, block, 0, stream, Q, K, V, Oo);
}

// Round 8
// 75.596 us; speedup vs baseline: 2.5382x; 1.7353x over previous
//
#include <hip/hip_runtime.h>

typedef short    s16x8 __attribute__((ext_vector_type(8)));
typedef float    f32x4 __attribute__((ext_vector_type(4)));
typedef unsigned u32x4 __attribute__((ext_vector_type(4)));

#define BB 32
#define SS 2048
#define DD 64
#define QBLK 64
#define KVBLK 64
#define NQB (SS / QBLK)          // 32
#define NTILES (SS / KVBLK)      // 32

#define QSCALE (0.125f * 1.44269504088896340736f)

// Per buffer: K [64 rows][64 cols] bf16 @0, row stride 128B, 16B-slot XOR (chunk^row&7), 8KB.
//             Vt [64 d][64 k'] bf16 @8192, k' = (kc>>1)*32 + l16*8 + (kc&1)*4 + r, same XOR, 8KB.
#define BUFSZ 16384
#define K_OFF 0
#define V_OFF 8192

union U8 { u32x4 u; s16x8 s; };

struct StageRegs { float v[2][8]; float4 k[2][2]; };

__device__ __forceinline__ unsigned pk2bf(float lo, float hi) {
  unsigned r;
  asm("v_cvt_pk_bf16_f32 %0, %1, %2" : "=v"(r) : "v"(lo), "v"(hi));
  return r;
}

// Drain LDS only (NOT vmem) then sync: prefetch loads stay in flight across barriers.
#define BARRIER() asm volatile("s_waitcnt lgkmcnt(0)\ns_barrier" ::: "memory")

__global__ __launch_bounds__(256, 4)
void attn_fwd(const float* __restrict__ Q, const float* __restrict__ K,
              const float* __restrict__ V, float* __restrict__ O) {
  __shared__ __align__(16) char smem[2 * BUFSZ];
  const int tid  = threadIdx.x;
  const int w    = tid >> 6;          // 0..3
  const int lane = tid & 63;
  const int l15  = lane & 15;
  const int l16  = lane >> 4;

  // XCD-aware swizzle (bijective: 1024 = 8 * 128): 4 batches per XCD L2.
  const int bid0  = blockIdx.x;
  const int wid   = (bid0 & 7) * 128 + (bid0 >> 3);
  const int batch = wid >> 5;
  const int qb    = wid & 31;
  const size_t bstride = (size_t)batch * SS * DD;
  const int qrow0 = qb * QBLK + w * 16;

  // ---- Q B-frags (col=q=l15, k=d=dh*32+l16*8+j), pre-scaled ----
  s16x8 aq[2];
#pragma unroll
  for (int dh = 0; dh < 2; ++dh) {
    const float* qp = Q + bstride + (size_t)(qrow0 + l15) * DD + dh * 32 + l16 * 8;
    const float4 x = *(const float4*)qp;
    const float4 y = *(const float4*)(qp + 4);
    U8 u;
    u.u = (u32x4){ pk2bf(x.x * QSCALE, x.y * QSCALE), pk2bf(x.z * QSCALE, x.w * QSCALE),
                   pk2bf(y.x * QSCALE, y.y * QSCALE), pk2bf(y.z * QSCALE, y.w * QSCALE) };
    aq[dh] = u.s;
  }

  // O^T accumulators: lane holds q=l15, d = dt*16 + l16*4 + r.
  f32x4 oT[4];
#pragma unroll
  for (int dt = 0; dt < 4; ++dt) oT[dt] = (f32x4){0.f, 0.f, 0.f, 0.f};
  float mrun = -1e30f;
  float lsum = 0.f;   // lane-local partial; reduced across l16 replicas at the END

  // ---- staging addresses ----
  // V: wave w covers k'-chunks c = 2w, 2w+1; lane = d column.
  //    chunk c <-> keys base + {0..3, 16..19}, base = (c>>2)*32 + (c&3)*4; k' = c*8+j.
  const float* gV = V + bstride + lane;
  const int vls0 = V_OFF + lane * 128 + (((2 * w + 0) ^ (lane & 7)) << 4);
  const int vls1 = V_OFF + lane * 128 + (((2 * w + 1) ^ (lane & 7)) << 4);
  // K: row kr = tid>>2, chunks kc0, kc0+1 (8 cols each).
  const int kr  = tid >> 2;
  const int kc0 = (tid & 3) * 2;
  const float* gK = K + bstride + (size_t)kr * DD + kc0 * 8;
  const int kls0 = K_OFF + kr * 128 + (((kc0 + 0) ^ (kr & 7)) << 4);
  const int kls1 = K_OFF + kr * 128 + (((kc0 + 1) ^ (kr & 7)) << 4);

  auto stage_load = [&](int t, StageRegs& S) {
    const int kb = t * KVBLK;
#pragma unroll
    for (int h = 0; h < 2; ++h) {
      const int c = 2 * w + h;
      const float* g = gV + (size_t)(kb + (c >> 2) * 32 + (c & 3) * 4) * DD;
#pragma unroll
      for (int i = 0; i < 4; ++i) {
        S.v[h][i]     = g[(size_t)i * DD];
        S.v[h][4 + i] = g[(size_t)(16 + i) * DD];
      }
    }
#pragma unroll
    for (int h = 0; h < 2; ++h) {
      const float* g = gK + (size_t)kb * DD + h * 8;
      S.k[h][0] = *(const float4*)g;
      S.k[h][1] = *(const float4*)(g + 4);
    }
  };

  auto stage_write = [&](int off, const StageRegs& S) {
#pragma unroll
    for (int h = 0; h < 2; ++h) {
      u32x4 vv = (u32x4){ pk2bf(S.v[h][0], S.v[h][1]), pk2bf(S.v[h][2], S.v[h][3]),
                          pk2bf(S.v[h][4], S.v[h][5]), pk2bf(S.v[h][6], S.v[h][7]) };
      *(u32x4*)(smem + off + (h ? vls1 : vls0)) = vv;
    }
#pragma unroll
    for (int h = 0; h < 2; ++h) {
      u32x4 kv = (u32x4){ pk2bf(S.k[h][0].x, S.k[h][0].y), pk2bf(S.k[h][0].z, S.k[h][0].w),
                          pk2bf(S.k[h][1].x, S.k[h][1].y), pk2bf(S.k[h][1].z, S.k[h][1].w) };
      *(u32x4*)(smem + off + (h ? kls1 : kls0)) = kv;
    }
  };

  auto compute = [&](int off) {
    // K A-frags: lane holds K[kc*16+l15][dh*32+l16*8+j]
    s16x8 bk[4][2];
#pragma unroll
    for (int kc = 0; kc < 4; ++kc)
#pragma unroll
      for (int dh = 0; dh < 2; ++dh)
        bk[kc][dh] = *(const s16x8*)(smem + off + K_OFF + (kc * 16 + l15) * 128 +
                                     (((dh * 4 + l16) ^ (l15 & 7)) << 4));

    // S^T = K·Q^T : lane holds q=l15, key = kc*16 + l16*4 + r
    f32x4 s[4];
    __builtin_amdgcn_s_setprio(1);
#pragma unroll
    for (int kc = 0; kc < 4; ++kc) {
      s[kc] = (f32x4){0.f, 0.f, 0.f, 0.f};
      s[kc] = __builtin_amdgcn_mfma_f32_16x16x32_bf16(bk[kc][0], aq[0], s[kc], 0, 0, 0);
      s[kc] = __builtin_amdgcn_mfma_f32_16x16x32_bf16(bk[kc][1], aq[1], s[kc], 0, 0, 0);
    }
    __builtin_amdgcn_s_setprio(0);

    // ---- online softmax, defer-max (THR=8, log2 domain); sum kept lane-local ----
    float m01 = fmaxf(fmaxf(fmaxf(s[0][0], s[0][1]), fmaxf(s[0][2], s[0][3])),
                      fmaxf(fmaxf(s[1][0], s[1][1]), fmaxf(s[1][2], s[1][3])));
    float m23 = fmaxf(fmaxf(fmaxf(s[2][0], s[2][1]), fmaxf(s[2][2], s[2][3])),
                      fmaxf(fmaxf(s[3][0], s[3][1]), fmaxf(s[3][2], s[3][3])));
    float mx = fmaxf(m01, m23);
    mx = fmaxf(mx, __shfl_xor(mx, 16));
    mx = fmaxf(mx, __shfl_xor(mx, 32));
    const int skip = __all(mx <= mrun + 8.0f);
    if (!skip) {
      const float mnew = fmaxf(mrun, mx);
      const float scl  = __builtin_amdgcn_exp2f(mrun - mnew);
      lsum *= scl;
#pragma unroll
      for (int dt = 0; dt < 4; ++dt) oT[dt] = oT[dt] * scl;
      mrun = mnew;
    }

    // V^T A-frags (issued here so ds_read latency overlaps the exp2/pack VALU work)
    s16x8 vt[4][2];
#pragma unroll
    for (int dt = 0; dt < 4; ++dt)
#pragma unroll
      for (int kc2 = 0; kc2 < 2; ++kc2)
        vt[dt][kc2] = *(const s16x8*)(smem + off + V_OFF + (dt * 16 + l15) * 128 +
                                      (((kc2 * 4 + l16) ^ (l15 & 7)) << 4));

    float p[4][4];
#pragma unroll
    for (int kc = 0; kc < 4; ++kc)
#pragma unroll
      for (int r = 0; r < 4; ++r)
        p[kc][r] = __builtin_amdgcn_exp2f(s[kc][r] - mrun);
    lsum += ((((p[0][0] + p[0][1]) + (p[0][2] + p[0][3])) +
              ((p[1][0] + p[1][1]) + (p[1][2] + p[1][3]))) +
             (((p[2][0] + p[2][1]) + (p[2][2] + p[2][3])) +
              ((p[3][0] + p[3][1]) + (p[3][2] + p[3][3]))));

    // P B-frags in regs: frag kc2, position j -> k' = kc2*32 + l16*8 + j
    U8 pb0, pb1;
    pb0.u = (u32x4){ pk2bf(p[0][0], p[0][1]), pk2bf(p[0][2], p[0][3]),
                     pk2bf(p[1][0], p[1][1]), pk2bf(p[1][2], p[1][3]) };
    pb1.u = (u32x4){ pk2bf(p[2][0], p[2][1]), pk2bf(p[2][2], p[2][3]),
                     pk2bf(p[3][0], p[3][1]), pk2bf(p[3][2], p[3][3]) };

    // O^T += V^T · P^T
    __builtin_amdgcn_s_setprio(1);
#pragma unroll
    for (int dt = 0; dt < 4; ++dt) {
      oT[dt] = __builtin_amdgcn_mfma_f32_16x16x32_bf16(vt[dt][0], pb0.s, oT[dt], 0, 0, 0);
      oT[dt] = __builtin_amdgcn_mfma_f32_16x16x32_bf16(vt[dt][1], pb1.s, oT[dt], 0, 0, 0);
    }
    __builtin_amdgcn_s_setprio(0);
  };

  // ---- pipelined main loop: 1 barrier per tile, vmem prefetch flies across barriers ----
  StageRegs A, C;
  stage_load(0, A);
  stage_write(0, A);
  BARRIER();
  for (int i = 0; i < NTILES / 2 - 1; ++i) {
    stage_load(2 * i + 1, C);
    compute(0);
    stage_write(BUFSZ, C);
    BARRIER();
    stage_load(2 * i + 2, A);
    compute(BUFSZ);
    stage_write(0, A);
    BARRIER();
  }
  stage_load(NTILES - 1, C);
  compute(0);                 // tile NTILES-2
  stage_write(BUFSZ, C);
  BARRIER();
  compute(BUFSZ);             // tile NTILES-1

  // ---- epilogue: reduce lane-local sums across the 4 replica groups, write O ----
  float lr = lsum;
  lr += __shfl_xor(lr, 16);
  lr += __shfl_xor(lr, 32);
  const float inv = 1.0f / lr;
  float* ob = O + bstride + (size_t)(qrow0 + l15) * DD + l16 * 4;
#pragma unroll
  for (int dt = 0; dt < 4; ++dt)
#pragma unroll
    for (int r = 0; r < 4; ++r)
      ob[dt * 16 + r] = oT[dt][r] * inv;
}

extern "C" void kernel_launch(void* const* d_in, const int* in_sizes, int n_in,
                              void* d_out, int out_size, void* d_ws, size_t ws_size,
                              hipStream_t stream) {
  const float* Q = (const float*)d_in[0];
  const float* K = (const float*)d_in[1];
  const float* V = (const float*)d_in[2];
  float* Oo = (float*)d_out;
  dim3 grid(BB * NQB);   // 1024
  dim3 block(256);       // 4 waves
  hipLaunchKernelGGL(attn_fwd, grid, block, 0, stream, Q, K, V, Oo);
}